// Round 7
// baseline (52.306 us; speedup 1.0000x reference)
//
#include <hip/hip_runtime.h>

// Loss = (1/B) * sum_{b,i} min_j ||s[b,i]-t[b,j]||^2  (Cl(3) scalar part of v*v = ||v||^2).
// Track per point the min of h = 0.5||s||^2 + 0.5||t||^2 - s.t = 0.5*d2;
// loss = (1/4) * 2 * sum(h) = 0.5 * sum(h).
#define BATCH 4
#define NPTS 8192
#define NTOT (BATCH * NPTS)   // 32768

constexpr int THREADS   = 256;
constexpr int S_PER_THR = 8;                      // source points per thread (regs)
constexpr int SRC_CHUNK = THREADS * S_PER_THR;    // 2048
constexpr int NSC       = NPTS / SRC_CHUNK;       // 4
constexpr int TGT_CHUNK = 128;                    // << only change vs R3 (was 256)
constexpr int NTC       = NPTS / TGT_CHUNK;       // 64 slabs
constexpr int R1_BLOCKS = 64;

// grid = B*NSC*NTC = 1024 blocks -> 4 blocks/CU -> 4 waves/SIMD.
__global__ __launch_bounds__(THREADS) void knn_partial_kernel(
        const float* __restrict__ src,   // (B, P, 3)
        const float* __restrict__ tgt,   // (B, P, 3)
        float* __restrict__ ws)          // (NTC, NTOT) partial h-mins
{
    int bid = blockIdx.x;
    int tc  = bid % NTC;
    int sc  = (bid / NTC) % NSC;
    int b   = bid / (NTC * NSC);

    __shared__ float4 tsh[TGT_CHUNK];

    // Stage target tile: (x, y, z, 0.5*||t||^2).
    if (threadIdx.x < TGT_CHUNK) {
        const float* tbase = tgt + ((size_t)b * NPTS + (size_t)tc * TGT_CHUNK) * 3;
        int k = threadIdx.x;
        float x = tbase[3 * k + 0];
        float y = tbase[3 * k + 1];
        float z = tbase[3 * k + 2];
        tsh[k] = make_float4(x, y, z, 0.5f * (x * x + y * y + z * z));
    }

    // My 8 source points in registers.
    const float* sbase = src + ((size_t)b * NPTS + (size_t)sc * SRC_CHUNK) * 3;
    float sx[S_PER_THR], sy[S_PER_THR], sz[S_PER_THR], mb[S_PER_THR];
    #pragma unroll
    for (int s = 0; s < S_PER_THR; ++s) {
        int i = threadIdx.x + s * THREADS;
        sx[s] = sbase[3 * i + 0];
        sy[s] = sbase[3 * i + 1];
        sz[s] = sbase[3 * i + 2];
        mb[s] = INFINITY;
    }
    __syncthreads();

    // Per j-pair per thread: 2 broadcast ds_read_b128 + 8*(6 fma + 1 min3).
    #pragma unroll 4
    for (int j = 0; j < TGT_CHUNK; j += 2) {
        float4 t0 = tsh[j];
        float4 t1 = tsh[j + 1];
        #pragma unroll
        for (int s = 0; s < S_PER_THR; ++s) {
            float m0 = fmaf(-sx[s], t0.x, fmaf(-sy[s], t0.y, fmaf(-sz[s], t0.z, t0.w)));
            float m1 = fmaf(-sx[s], t1.x, fmaf(-sy[s], t1.y, fmaf(-sz[s], t1.z, t1.w)));
            mb[s] = fminf(mb[s], fminf(m0, m1));   // -> v_min3_f32
        }
    }

    // h = min_m + 0.5||s||^2 ; plain store into this target-chunk's slab.
    float* wbase = ws + (size_t)tc * NTOT + (size_t)b * NPTS + (size_t)sc * SRC_CHUNK;
    #pragma unroll
    for (int s = 0; s < S_PER_THR; ++s) {
        float hs = 0.5f * (sx[s] * sx[s] + sy[s] * sy[s] + sz[s] * sz[s]);
        wbase[threadIdx.x + s * THREADS] = mb[s] + hs;
    }
}

// Stage 1: 64 blocks; each handles 512 points: min across the 64 slabs, sum.
__global__ __launch_bounds__(256) void reduce1_kernel(
        const float* __restrict__ ws,
        float* __restrict__ partials)
{
    __shared__ float acc[256];
    int base = blockIdx.x * (NTOT / R1_BLOCKS);   // 512 points per block
    float a = 0.0f;
    #pragma unroll
    for (int p = 0; p < 2; ++p) {
        int i = base + threadIdx.x + p * 256;
        float m = INFINITY;
        #pragma unroll 8
        for (int sl = 0; sl < NTC; ++sl)
            m = fminf(m, ws[(size_t)sl * NTOT + i]);
        a += m;
    }
    acc[threadIdx.x] = a;
    __syncthreads();
    for (int off = 128; off > 0; off >>= 1) {
        if (threadIdx.x < off) acc[threadIdx.x] += acc[threadIdx.x + off];
        __syncthreads();
    }
    if (threadIdx.x == 0) partials[blockIdx.x] = acc[0];
}

// Stage 2: one wave sums the 64 partials; loss = 0.5 * total.
__global__ __launch_bounds__(64) void reduce2_kernel(
        const float* __restrict__ partials,
        float* __restrict__ out)
{
    float v = partials[threadIdx.x];
    #pragma unroll
    for (int off = 32; off > 0; off >>= 1)
        v += __shfl_down(v, off, 64);
    if (threadIdx.x == 0) out[0] = v * 0.5f;
}

extern "C" void kernel_launch(void* const* d_in, const int* in_sizes, int n_in,
                              void* d_out, int out_size, void* d_ws, size_t ws_size,
                              hipStream_t stream) {
    const float* src = (const float*)d_in[0];   // source_cloud (4, 8192, 3) f32
    const float* tgt = (const float*)d_in[1];   // target_cloud (4, 8192, 3) f32
    // d_in[2] = cayley (8,8,8) — Euclidean; scalar part of v*v == ||v||^2
    float* out = (float*)d_out;

    // Workspace: slabs (8 MiB) | partials (256 B)
    float* ws       = (float*)d_ws;
    float* partials = (float*)((char*)d_ws + (size_t)NTC * NTOT * sizeof(float));

    knn_partial_kernel<<<BATCH * NSC * NTC, THREADS, 0, stream>>>(src, tgt, ws);
    reduce1_kernel<<<R1_BLOCKS, 256, 0, stream>>>(ws, partials);
    reduce2_kernel<<<1, 64, 0, stream>>>(partials, out);
}

// Round 8
// 39.619 us; speedup vs baseline: 1.3202x; 1.3202x over previous
//
#include <hip/hip_runtime.h>

// Loss = (1/B) * sum_{b,i} min_j ||s[b,i]-t[b,j]||^2  (Cl(3) scalar: v*v|_1 = ||v||^2).
// d2 = ||s||^2 + 2h, h = 0.5||t||^2 - s.t. The h-tile is computed on the MATRIX pipe
// via split-bf16 (hi+lo) MFMA 32x32x16: A row=target holds k0..3=(x,y,z,n)_hi,
// k4..7=(x,y,z,n)_lo; B col=source: B1=(-s_hi,1)x2, B2=(-s_lo,0)x2.
// M1+M2 = n - t.(s_hi+s_lo) = h up to ~1e-4 (lo x lo terms captured by B's dup halves).
#define BATCH 4
#define NPTS 8192
#define NTOT (BATCH * NPTS)   // 32768

typedef __attribute__((ext_vector_type(8)))  short  short8;
typedef __attribute__((ext_vector_type(16))) float  f32x16;

__device__ __forceinline__ unsigned short f2bf(float f) {   // RNE f32->bf16
    unsigned u = __float_as_uint(f);
    unsigned r = u + 0x7FFFu + ((u >> 16) & 1u);
    return (unsigned short)(r >> 16);
}
__device__ __forceinline__ float bf2f(unsigned short s) {
    return __uint_as_float(((unsigned)s) << 16);
}

// Pack target j as 8 bf16: (x,y,z,n)_hi | (x,y,z,n)_lo, n = 0.5||t||^2.
__global__ __launch_bounds__(256) void prep_kernel(
        const float* __restrict__ tgt, short8* __restrict__ packed)
{
    int j = blockIdx.x * 256 + threadIdx.x;
    float x = tgt[3*j+0], y = tgt[3*j+1], z = tgt[3*j+2];
    float n = 0.5f * (x*x + y*y + z*z);
    unsigned short hx = f2bf(x), hy = f2bf(y), hz = f2bf(z), hn = f2bf(n);
    unsigned short lx = f2bf(x - bf2f(hx)), ly = f2bf(y - bf2f(hy)),
                   lz = f2bf(z - bf2f(hz)), ln = f2bf(n - bf2f(hn));
    short8 v = { (short)hx,(short)hy,(short)hz,(short)hn,
                 (short)lx,(short)ly,(short)lz,(short)ln };
    packed[j] = v;
}

// Block = (b, 128-source chunk, target half). grid = 4*64*2 = 512 (2 blocks/CU).
// Each wave: 32 sources (B frags, built once) x 4096 targets (128 MFMA tiles).
__global__ __launch_bounds__(256) void knn_mfma_kernel(
        const float* __restrict__ src, const short8* __restrict__ packed,
        float* __restrict__ slab)     // (2, NTOT) per-half d2-mins
{
    __shared__ short8 tlds[512];      // 16 tiles (512 targets) staged per group, 8 KB

    int gid   = blockIdx.x;
    int half  = gid & 1;
    int chunk = (gid >> 1) & 63;
    int b     = gid >> 7;
    int lane  = threadIdx.x & 63;
    int wave  = threadIdx.x >> 6;
    int col   = lane & 31;
    bool lo   = (lane < 32);

    int p_local = chunk * 128 + wave * 32 + col;   // my source (cols of C)

    float sx = 0.f, sy = 0.f, sz = 0.f;
    if (lo) {
        const float* sp = src + ((size_t)b * NPTS + p_local) * 3;
        sx = sp[0]; sy = sp[1]; sz = sp[2];
    }
    float ns2 = sx*sx + sy*sy + sz*sz;

    // Source fragments (negated, split hi/lo). Lanes >= 32 hold k8..15 = zeros.
    float nx = -sx, ny = -sy, nz = -sz;
    unsigned short hx = f2bf(nx), hy = f2bf(ny), hz = f2bf(nz);
    unsigned short lx = f2bf(nx - bf2f(hx)), ly = f2bf(ny - bf2f(hy)),
                   lz = f2bf(nz - bf2f(hz));
    const short ONE = (short)0x3F80;   // bf16(1.0)
    short8 B1 = {0,0,0,0,0,0,0,0}, B2 = {0,0,0,0,0,0,0,0};
    if (lo) {
        B1 = short8{ (short)hx,(short)hy,(short)hz, ONE,
                     (short)hx,(short)hy,(short)hz, ONE };
        B2 = short8{ (short)lx,(short)ly,(short)lz, 0,
                     (short)lx,(short)ly,(short)lz, 0 };
    }

    const short8* tp = packed + (size_t)b * NPTS + (size_t)half * 4096;

    float mb[8];
    #pragma unroll
    for (int i = 0; i < 8; ++i) mb[i] = INFINITY;

    for (int g = 0; g < 8; ++g) {                  // 8 groups x 16 tiles
        __syncthreads();
        tlds[threadIdx.x]       = tp[g*512 + threadIdx.x];
        tlds[threadIdx.x + 256] = tp[g*512 + 256 + threadIdx.x];
        __syncthreads();
        #pragma unroll 4
        for (int tt = 0; tt < 16; ++tt) {
            short8 A = {0,0,0,0,0,0,0,0};
            if (lo) A = tlds[tt*32 + col];         // row = target, 16 B/lane
            f32x16 c = {0,0,0,0,0,0,0,0,0,0,0,0,0,0,0,0};
            c = __builtin_amdgcn_mfma_f32_32x32x16_bf16(A, B1, c, 0, 0, 0);
            c = __builtin_amdgcn_mfma_f32_32x32x16_bf16(A, B2, c, 0, 0, 0);
            // running min over this tile's 32 targets (16 rows here, 16 in lane^32)
            #pragma unroll
            for (int i = 0; i < 8; ++i)
                mb[i] = fminf(mb[i], fminf(c[2*i], c[2*i+1]));
        }
    }

    float v = fminf(fminf(fminf(mb[0],mb[1]), fminf(mb[2],mb[3])),
                    fminf(fminf(mb[4],mb[5]), fminf(mb[6],mb[7])));
    v = fminf(v, __shfl_xor(v, 32, 64));           // other 16 rows live in lane^32
    if (lo)
        slab[(size_t)half * NTOT + (size_t)b * NPTS + p_local] = fmaf(2.0f, v, ns2);
}

// Sum of per-point min over the 2 target halves; 64 blocks x 512 points.
__global__ __launch_bounds__(256) void reduce1_kernel(
        const float* __restrict__ slab, float* __restrict__ partials)
{
    __shared__ float acc[256];
    int base = blockIdx.x * 512;
    float a = 0.f;
    #pragma unroll
    for (int p = 0; p < 2; ++p) {
        int i = base + threadIdx.x + p * 256;
        a += fminf(slab[i], slab[NTOT + i]);
    }
    acc[threadIdx.x] = a;
    __syncthreads();
    for (int off = 128; off > 0; off >>= 1) {
        if (threadIdx.x < off) acc[threadIdx.x] += acc[threadIdx.x + off];
        __syncthreads();
    }
    if (threadIdx.x == 0) partials[blockIdx.x] = acc[0];
}

__global__ __launch_bounds__(64) void reduce2_kernel(
        const float* __restrict__ partials, float* __restrict__ out)
{
    float v = partials[threadIdx.x];
    #pragma unroll
    for (int off = 32; off > 0; off >>= 1)
        v += __shfl_down(v, off, 64);
    if (threadIdx.x == 0) out[0] = v * 0.25f;      // mean over BATCH
}

extern "C" void kernel_launch(void* const* d_in, const int* in_sizes, int n_in,
                              void* d_out, int out_size, void* d_ws, size_t ws_size,
                              hipStream_t stream) {
    const float* src = (const float*)d_in[0];   // source_cloud (4, 8192, 3) f32
    const float* tgt = (const float*)d_in[1];   // target_cloud (4, 8192, 3) f32
    // d_in[2] = cayley (8,8,8) — Euclidean; scalar part of v*v == ||v||^2
    float* out = (float*)d_out;

    // ws: packed targets (512 KiB) | slab (256 KiB) | partials (256 B)
    short8* packed   = (short8*)d_ws;
    float*  slab     = (float*)((char*)d_ws + (size_t)NTOT * sizeof(short8));
    float*  partials = slab + 2 * NTOT;

    prep_kernel<<<NTOT / 256, 256, 0, stream>>>(tgt, packed);
    knn_mfma_kernel<<<512, 256, 0, stream>>>(src, packed, slab);
    reduce1_kernel<<<64, 256, 0, stream>>>(slab, partials);
    reduce2_kernel<<<1, 64, 0, stream>>>(partials, out);
}